// Round 19
// baseline (160.115 us; speedup 1.0000x reference)
//
#include <hip/hip_runtime.h>
#include <cstdint>
#include <cstddef>

#define HDIM 512
#define NM 32
#define NBATCH 4096
#define NNODE 65536
#define CAP 16

typedef float v4f __attribute__((ext_vector_type(4)));

// ---------------- Threefry-2x32-20, key = (0,1)  (jax.random.key(1)) -------
__device__ __forceinline__ unsigned rotl32(unsigned x, unsigned d) {
  return (x << d) | (x >> (32u - d));
}

__device__ __forceinline__ void threefry2x32(unsigned& x0, unsigned& x1) {
  const unsigned ks0 = 0u, ks1 = 1u, ks2 = 0x1BD11BDBu; // 0^1^0x1BD11BDA
  x0 += ks0; x1 += ks1;
#define TF_RND(r) { x0 += x1; x1 = rotl32(x1, (r)); x1 ^= x0; }
  TF_RND(13) TF_RND(15) TF_RND(26) TF_RND(6)
  x0 += ks1; x1 += ks2 + 1u;
  TF_RND(17) TF_RND(29) TF_RND(16) TF_RND(24)
  x0 += ks2; x1 += ks0 + 2u;
  TF_RND(13) TF_RND(15) TF_RND(26) TF_RND(6)
  x0 += ks0; x1 += ks1 + 3u;
  TF_RND(17) TF_RND(29) TF_RND(16) TF_RND(24)
  x0 += ks1; x1 += ks2 + 4u;
  TF_RND(13) TF_RND(15) TF_RND(26) TF_RND(6)
  x0 += ks2; x1 += ks0 + 5u;
#undef TF_RND
}

// ---------------- kernel 1: zero cnt (blocks 0..63) + b1 gemm (64..575) ----
__global__ __launch_bounds__(256) void zero_and_b1(
    const float* __restrict__ Ws, const float* __restrict__ Wd,
    const float* __restrict__ Wq, float* __restrict__ M2T,
    int* __restrict__ cnt, int* __restrict__ ovf_cnt) {
  const int bid = blockIdx.x;
  const int tid = threadIdx.x;
  if (bid < 64) {
    const int t = bid * 256 + tid;       // 16384 int4 -> 64K ints
    ((int4*)cnt)[t] = make_int4(0, 0, 0, 0);
    if (t == 0) *ovf_cnt = 0;
    return;
  }
  // ---- b1 gemm part ----
  constexpr int BK = 32, LDT = 36;  // 32 + 4 pad
  __shared__ float Ast[BK][LDT];
  __shared__ float Bst[BK][LDT];
  const int gb = bid - 64;               // 0..511
  const int rt = gb >> 4;                // 32 row-tiles (combined c)
  const int ct = gb & 15;                // 16 col-tiles (e)
  const int row0 = rt * 32;
  const int col0 = ct * 32;
  const float* Abase = (row0 < 512) ? Ws : Wd;
  const int arow0 = (row0 < 512) ? row0 : row0 - 512;
  const int tx = tid & 15, ty = tid >> 4;
  const int lr = tid >> 3;               // 0..31
  const int lc = (tid & 7) * 4;          // 0,4,..,28
  float acc[2][2] = {};
  for (int k0 = 0; k0 < 512; k0 += BK) {
    const float4 va = *(const float4*)(Abase + (size_t)(arow0 + lr) * 1536 + k0 + lc);
    const float4 vb = *(const float4*)(Wq + (size_t)(col0 + lr) * 512 + k0 + lc);
    Ast[lc + 0][lr] = va.x; Ast[lc + 1][lr] = va.y;
    Ast[lc + 2][lr] = va.z; Ast[lc + 3][lr] = va.w;
    Bst[lc + 0][lr] = vb.x; Bst[lc + 1][lr] = vb.y;
    Bst[lc + 2][lr] = vb.z; Bst[lc + 3][lr] = vb.w;
    __syncthreads();
#pragma unroll
    for (int k = 0; k < BK; ++k) {
      const float a0 = Ast[k][ty * 2], a1 = Ast[k][ty * 2 + 1];
      const float b0 = Bst[k][tx * 2], b1 = Bst[k][tx * 2 + 1];
      acc[0][0] += a0 * b0; acc[0][1] += a0 * b1;
      acc[1][0] += a1 * b0; acc[1][1] += a1 * b1;
    }
    __syncthreads();
  }
#pragma unroll
  for (int i = 0; i < 2; ++i) {
    float2 o;
    o.x = acc[i][0]; o.y = acc[i][1];
    *(float2*)(M2T + (size_t)(row0 + ty * 2 + i) * 512 + col0 + tx * 2) = o;
  }
}

// ---------------- kernel 2: gemm_v (blocks 0..511) + build_index (512..1023)
// gemm_v R14-exact: 128x64 tile, 8x8 micro, two 128-thread k-teams
// (in-block split-K), merge V = accT0 + accT1 via LDS.
__global__ __launch_bounds__(256) void gemmv_and_index(
    const float* __restrict__ hs, const float* __restrict__ hd,
    const int* __restrict__ cur, const float* __restrict__ Bm,
    float* __restrict__ C,
    const int* __restrict__ neigh, const int* __restrict__ lens,
    int* __restrict__ cnt, int* __restrict__ bucket,
    int* __restrict__ ovf_cnt, int* __restrict__ ovf_list) {
  const int bid = blockIdx.x;
  const int tid = threadIdx.x;
  if (bid >= 512) {
    // ---- build_index part ----
    const int t = (bid - 512) * 256 + tid;   // t in [0, B*M)
    const int b = t >> 5, m = t & 31;
    if (m < lens[b]) {
      const int n = neigh[t];
      const int slot = atomicAdd(&cnt[n], 1);
      if (slot < CAP) bucket[n * CAP + slot] = t;
      else { const int o = atomicAdd(ovf_cnt, 1); ovf_list[o] = t; }
    }
    return;
  }
  // ---- gemm_v part ----
  __shared__ __align__(16) char smem[51200];
  float* As = (float*)smem;              // [2][32][132] = 33792 B
  float* Bs = (float*)(smem + 33792);    // [2][32][68]  = 17408 B
  float* mg = (float*)smem;              // [128][65] merge, aliases As

  const int team = tid >> 7;             // k-half
  const int lt = tid & 127;
  const int swz = (bid & 7) * 64 + (bid >> 3);  // 512 % 8 == 0
  const int row0 = (swz >> 4) * 128;     // 32 row-tiles
  const int col0 = (swz & 15) * 64;      // 16 col-tiles
  const int tx = tid & 7;                // c-block 0..7
  const int ty = (tid >> 3) & 15;        // r-block 0..15
  const int r0 = lt >> 3;                // staging row base 0..15
  const int cq = (lt & 7) * 4;           // staging k-offset 0,4,..,28
  const int kb = team * 256;
  const int aoff = team * 4224;          // 32*132
  const int boff = team * 2176;          // 32*68

  size_t na[8];
#pragma unroll
  for (int p = 0; p < 8; ++p)
    na[p] = (size_t)cur[row0 + r0 + 16 * p] * HDIM + kb + cq;
  const float* bbase = Bm + (size_t)(col0 + r0) * 512 + kb + cq;

  float acc[8][8] = {};
#pragma unroll 1
  for (int t = 0; t < 8; ++t) {
    const int k0 = t * 32;
    float4 va[8], vd[8], vb[4];
#pragma unroll
    for (int p = 0; p < 8; ++p) {
      va[p] = *(const float4*)(hs + na[p] + k0);
      vd[p] = *(const float4*)(hd + na[p] + k0);
    }
#pragma unroll
    for (int p = 0; p < 4; ++p)
      vb[p] = *(const float4*)(bbase + p * (16 * 512) + k0);
    __syncthreads();   // previous tile's compute finished before overwrite
#pragma unroll
    for (int p = 0; p < 8; ++p) {
      const int r = r0 + 16 * p;
      As[aoff + (cq + 0) * 132 + r] = va[p].x + vd[p].x;
      As[aoff + (cq + 1) * 132 + r] = va[p].y + vd[p].y;
      As[aoff + (cq + 2) * 132 + r] = va[p].z + vd[p].z;
      As[aoff + (cq + 3) * 132 + r] = va[p].w + vd[p].w;
    }
#pragma unroll
    for (int p = 0; p < 4; ++p) {
      const int r = r0 + 16 * p;
      Bs[boff + (cq + 0) * 68 + r] = vb[p].x;
      Bs[boff + (cq + 1) * 68 + r] = vb[p].y;
      Bs[boff + (cq + 2) * 68 + r] = vb[p].z;
      Bs[boff + (cq + 3) * 68 + r] = vb[p].w;
    }
    __syncthreads();
#pragma unroll
    for (int k = 0; k < 32; ++k) {
      const float4 a0 = *(const float4*)&As[aoff + k * 132 + ty * 8];
      const float4 a1 = *(const float4*)&As[aoff + k * 132 + ty * 8 + 4];
      const float4 b0 = *(const float4*)&Bs[boff + k * 68 + tx * 8];
      const float4 b1 = *(const float4*)&Bs[boff + k * 68 + tx * 8 + 4];
      const float a[8] = {a0.x, a0.y, a0.z, a0.w, a1.x, a1.y, a1.z, a1.w};
      const float bb[8] = {b0.x, b0.y, b0.z, b0.w, b1.x, b1.y, b1.z, b1.w};
#pragma unroll
      for (int i = 0; i < 8; ++i)
#pragma unroll
        for (int j = 0; j < 8; ++j) acc[i][j] += a[i] * bb[j];
    }
  }
  __syncthreads();   // all compute done; safe to reuse As as merge buffer
  if (team == 1) {
#pragma unroll
    for (int i = 0; i < 8; ++i)
#pragma unroll
      for (int j = 0; j < 8; ++j)
        mg[lt * 65 + i * 8 + j] = acc[i][j];
  }
  __syncthreads();
  if (team == 0) {
#pragma unroll
    for (int i = 0; i < 8; ++i) {
#pragma unroll
      for (int j = 0; j < 8; ++j)
        acc[i][j] = acc[i][j] + mg[lt * 65 + i * 8 + j];  // T0 + T1 order
      float* cp = C + (size_t)(row0 + ty * 8 + i) * 1024 + col0 + tx * 8;
      float4 o0, o1;
      o0.x = acc[i][0]; o0.y = acc[i][1]; o0.z = acc[i][2]; o0.w = acc[i][3];
      o1.x = acc[i][4]; o1.y = acc[i][5]; o1.z = acc[i][6]; o1.w = acc[i][7];
      *(float4*)cp = o0;
      *(float4*)(cp + 4) = o1;
    }
  }
}

// ---------------- streaming compat: TWO nodes per wave + ovf drain ---------
// Both nodes' 8 global loads issue back-to-back (2x memory-level parallelism);
// node B's loads hide under node A's dot+reduce tail. Arithmetic identical.
__global__ __launch_bounds__(256) void stream_compat(
    const float* __restrict__ hs, const float* __restrict__ hd,
    const float* __restrict__ V, const int* __restrict__ cnt,
    const int* __restrict__ bucket, const int* __restrict__ ovf_cnt,
    const int* __restrict__ ovf_list, const int* __restrict__ neigh,
    float* __restrict__ compat) {
  const int n = blockIdx.x * 8 + (threadIdx.x >> 6) * 2;  // 2 nodes per wave
  const int lane = threadIdx.x & 63;
  const int c0 = cnt[n], c1 = cnt[n + 1];
  const v4f* a4 = (const v4f*)(hs + (size_t)n * HDIM);
  const v4f* c4 = (const v4f*)(hd + (size_t)n * HDIM);
  const v4f a0 = __builtin_nontemporal_load(a4 + lane * 2);
  const v4f a1 = __builtin_nontemporal_load(a4 + lane * 2 + 1);
  const v4f b0 = __builtin_nontemporal_load(c4 + lane * 2);
  const v4f b1 = __builtin_nontemporal_load(c4 + lane * 2 + 1);
  const v4f* e4 = (const v4f*)(hs + (size_t)(n + 1) * HDIM);
  const v4f* f4 = (const v4f*)(hd + (size_t)(n + 1) * HDIM);
  const v4f e0 = __builtin_nontemporal_load(e4 + lane * 2);
  const v4f e1 = __builtin_nontemporal_load(e4 + lane * 2 + 1);
  const v4f f0 = __builtin_nontemporal_load(f4 + lane * 2);
  const v4f f1 = __builtin_nontemporal_load(f4 + lane * 2 + 1);
  if (c0 != 0) {
    const int cc = (c0 < CAP) ? c0 : CAP;
    for (int e = 0; e < cc; ++e) {
      const int t = bucket[n * CAP + e];
      const int b = t >> 5;
      const float4* vrow = (const float4*)(V + (size_t)b * (2 * HDIM));
      const float4 w0 = vrow[lane * 2], w1 = vrow[lane * 2 + 1];
      const float4 u0 = vrow[128 + lane * 2], u1 = vrow[128 + lane * 2 + 1];
      float acc = a0.x * w0.x + a0.y * w0.y + a0.z * w0.z + a0.w * w0.w
                + a1.x * w1.x + a1.y * w1.y + a1.z * w1.z + a1.w * w1.w
                + b0.x * u0.x + b0.y * u0.y + b0.z * u0.z + b0.w * u0.w
                + b1.x * u1.x + b1.y * u1.y + b1.z * u1.z + b1.w * u1.w;
#pragma unroll
      for (int off = 32; off >= 1; off >>= 1) acc += __shfl_xor(acc, off);
      if (lane == 0) compat[t] = acc;
    }
  }
  if (c1 != 0) {
    const int cc = (c1 < CAP) ? c1 : CAP;
    for (int e = 0; e < cc; ++e) {
      const int t = bucket[(n + 1) * CAP + e];
      const int b = t >> 5;
      const float4* vrow = (const float4*)(V + (size_t)b * (2 * HDIM));
      const float4 w0 = vrow[lane * 2], w1 = vrow[lane * 2 + 1];
      const float4 u0 = vrow[128 + lane * 2], u1 = vrow[128 + lane * 2 + 1];
      float acc = e0.x * w0.x + e0.y * w0.y + e0.z * w0.z + e0.w * w0.w
                + e1.x * w1.x + e1.y * w1.y + e1.z * w1.z + e1.w * w1.w
                + f0.x * u0.x + f0.y * u0.y + f0.z * u0.z + f0.w * u0.w
                + f1.x * u1.x + f1.y * u1.y + f1.z * u1.z + f1.w * u1.w;
#pragma unroll
      for (int off = 32; off >= 1; off >>= 1) acc += __shfl_xor(acc, off);
      if (lane == 0) compat[t] = acc;
    }
  }
  // overflow drain (ovf is ~always empty; disjoint t-set -> no race)
  if (blockIdx.x < 32) {
    const int nw = *ovf_cnt;
    for (int e = blockIdx.x * 4 + (threadIdx.x >> 6); e < nw; e += 128) {
      const int t = ovf_list[e];
      const int b = t >> 5;
      const int nn = neigh[t];
      const float4* aa4 = (const float4*)(hs + (size_t)nn * HDIM);
      const float4* cc4 = (const float4*)(hd + (size_t)nn * HDIM);
      const float4 oa0 = aa4[lane * 2], oa1 = aa4[lane * 2 + 1];
      const float4 ob0 = cc4[lane * 2], ob1 = cc4[lane * 2 + 1];
      const float4* vrow = (const float4*)(V + (size_t)b * (2 * HDIM));
      const float4 w0 = vrow[lane * 2], w1 = vrow[lane * 2 + 1];
      const float4 u0 = vrow[128 + lane * 2], u1 = vrow[128 + lane * 2 + 1];
      float acc = oa0.x * w0.x + oa0.y * w0.y + oa0.z * w0.z + oa0.w * w0.w
                + oa1.x * w1.x + oa1.y * w1.y + oa1.z * w1.z + oa1.w * w1.w
                + ob0.x * u0.x + ob0.y * u0.y + ob0.z * u0.z + ob0.w * u0.w
                + ob1.x * u1.x + ob1.y * u1.y + ob1.z * u1.z + ob1.w * u1.w;
#pragma unroll
      for (int off = 32; off >= 1; off >>= 1) acc += __shfl_xor(acc, off);
      if (lane == 0) compat[t] = acc;
    }
  }
}

// ---------------- per-b: Gumbel argmax + log-softmax (one wave per b) ------
__global__ __launch_bounds__(256) void finalize_kernel(
    const float* __restrict__ compat, const int* __restrict__ neigh,
    const int* __restrict__ lengths, const int* __restrict__ cur,
    float* __restrict__ out) {
  const int b = blockIdx.x * 4 + (threadIdx.x >> 6);
  const int tid = threadIdx.x & 63;
  const int len = lengths[b];
  const bool valid = tid < NM;
  const float NEGMAX = -3.402823466e38f;
  float logit = NEGMAX;
  if (valid) {
    const float cm = compat[b * NM + tid] / 22.62741699796952f;  // / sqrt(512)
    logit = (tid < len) ? cm : -1e9f;
  }
  float z = NEGMAX;
  int zi = 1 << 20;
  if (valid) {
    // JAX partitionable threefry: counter = 64-bit flat index,
    // draw = out0 ^ out1 of threefry2x32(key=(0,1), (hi, lo)).
    const unsigned i_lo = (unsigned)b * 32u + (unsigned)tid;
    unsigned x0 = 0u;
    unsigned x1 = i_lo;
    threefry2x32(x0, x1);
    const unsigned bits = x0 ^ x1;
    const float fu = __uint_as_float((bits >> 9) | 0x3f800000u) - 1.0f;
    const float uu = fmaxf(1e-8f, fu + 1e-8f);
    const float g = -logf(-logf(uu));
    z = logit + g;
    zi = tid;
  }
#pragma unroll
  for (int off = 32; off >= 1; off >>= 1) {
    const float oz = __shfl_xor(z, off);
    const int oi = __shfl_xor(zi, off);
    if (oz > z || (oz == z && oi < zi)) { z = oz; zi = oi; }
  }
  float ml = logit;
#pragma unroll
  for (int off = 32; off >= 1; off >>= 1) ml = fmaxf(ml, __shfl_xor(ml, off));
  float ex = valid ? expf(logit - ml) : 0.f;
#pragma unroll
  for (int off = 32; off >= 1; off >>= 1) ex += __shfl_xor(ex, off);
  const float lsel = __shfl(logit, zi);
  if (tid == 0) {
    float lp = lsel - ml - logf(ex);
    int act = neigh[b * NM + zi];
    if (len <= 0) { act = cur[b]; lp = 0.f; }
    out[b] = (float)act;
    out[NBATCH + b] = lp;
  }
}

extern "C" void kernel_launch(void* const* d_in, const int* in_sizes, int n_in,
                              void* d_out, int out_size, void* d_ws, size_t ws_size,
                              hipStream_t stream) {
  const float* hs = (const float*)d_in[0];
  const float* hd = (const float*)d_in[1];
  const float* Ws = (const float*)d_in[2];
  const float* Wd = (const float*)d_in[3];
  const float* Wq = (const float*)d_in[4];
  const int* cur = (const int*)d_in[6];
  const int* neigh = (const int*)d_in[7];
  const int* lens = (const int*)d_in[8];
  float* out = (float*)d_out;

  char* ws = (char*)d_ws;
  size_t off = 0;
  int* cnt = (int*)(ws + off);        off += (size_t)NNODE * 4;        // 256 KB
  int* ovf_cnt = (int*)(ws + off);    off += 256;                      // pad
  int* bucket = (int*)(ws + off);     off += (size_t)NNODE * CAP * 4;  // 4 MB
  int* ovf_list = (int*)(ws + off);   off += (size_t)NBATCH * NM * 4;  // 512 KB
  float* compat = (float*)(ws + off); off += (size_t)NBATCH * NM * 4;  // 512 KB
  float* M2T = (float*)(ws + off);    off += (size_t)1024 * 512 * 4;       // 2 MB
  float* V = (float*)(ws + off);      off += (size_t)NBATCH * 1024 * 4;    // 16 MB

  hipLaunchKernelGGL(zero_and_b1, dim3(64 + 512), dim3(256), 0, stream,
                     Ws, Wd, Wq, M2T, cnt, ovf_cnt);
  hipLaunchKernelGGL(gemmv_and_index, dim3(512 + NBATCH * NM / 256), dim3(256), 0, stream,
                     hs, hd, cur, M2T, V, neigh, lens, cnt, bucket, ovf_cnt, ovf_list);
  hipLaunchKernelGGL(stream_compat, dim3(NNODE / 8), dim3(256), 0, stream,
                     hs, hd, V, cnt, bucket, ovf_cnt, ovf_list, neigh, compat);
  hipLaunchKernelGGL(finalize_kernel, dim3(NBATCH / 4), dim3(256), 0, stream,
                     compat, neigh, lens, cur, out);
}

// Round 20
// 151.266 us; speedup vs baseline: 1.0585x; 1.0585x over previous
//
#include <hip/hip_runtime.h>
#include <cstdint>
#include <cstddef>

#define HDIM 512
#define NM 32
#define NBATCH 4096
#define NNODE 65536
#define CAP 16

typedef float v4f __attribute__((ext_vector_type(4)));

// ---------------- Threefry-2x32-20, key = (0,1)  (jax.random.key(1)) -------
__device__ __forceinline__ unsigned rotl32(unsigned x, unsigned d) {
  return (x << d) | (x >> (32u - d));
}

__device__ __forceinline__ void threefry2x32(unsigned& x0, unsigned& x1) {
  const unsigned ks0 = 0u, ks1 = 1u, ks2 = 0x1BD11BDBu; // 0^1^0x1BD11BDA
  x0 += ks0; x1 += ks1;
#define TF_RND(r) { x0 += x1; x1 = rotl32(x1, (r)); x1 ^= x0; }
  TF_RND(13) TF_RND(15) TF_RND(26) TF_RND(6)
  x0 += ks1; x1 += ks2 + 1u;
  TF_RND(17) TF_RND(29) TF_RND(16) TF_RND(24)
  x0 += ks2; x1 += ks0 + 2u;
  TF_RND(13) TF_RND(15) TF_RND(26) TF_RND(6)
  x0 += ks0; x1 += ks1 + 3u;
  TF_RND(17) TF_RND(29) TF_RND(16) TF_RND(24)
  x0 += ks1; x1 += ks2 + 4u;
  TF_RND(13) TF_RND(15) TF_RND(26) TF_RND(6)
  x0 += ks2; x1 += ks0 + 5u;
#undef TF_RND
}

// ---------------- kernel 1: zero cnt (blocks 0..63) + b1 gemm (64..575) ----
__global__ __launch_bounds__(256) void zero_and_b1(
    const float* __restrict__ Ws, const float* __restrict__ Wd,
    const float* __restrict__ Wq, float* __restrict__ M2T,
    int* __restrict__ cnt, int* __restrict__ ovf_cnt) {
  const int bid = blockIdx.x;
  const int tid = threadIdx.x;
  if (bid < 64) {
    const int t = bid * 256 + tid;       // 16384 int4 -> 64K ints
    ((int4*)cnt)[t] = make_int4(0, 0, 0, 0);
    if (t == 0) *ovf_cnt = 0;
    return;
  }
  // ---- b1 gemm part ----
  constexpr int BK = 32, LDT = 36;  // 32 + 4 pad
  __shared__ float Ast[BK][LDT];
  __shared__ float Bst[BK][LDT];
  const int gb = bid - 64;               // 0..511
  const int rt = gb >> 4;                // 32 row-tiles (combined c)
  const int ct = gb & 15;                // 16 col-tiles (e)
  const int row0 = rt * 32;
  const int col0 = ct * 32;
  const float* Abase = (row0 < 512) ? Ws : Wd;
  const int arow0 = (row0 < 512) ? row0 : row0 - 512;
  const int tx = tid & 15, ty = tid >> 4;
  const int lr = tid >> 3;               // 0..31
  const int lc = (tid & 7) * 4;          // 0,4,..,28
  float acc[2][2] = {};
  for (int k0 = 0; k0 < 512; k0 += BK) {
    const float4 va = *(const float4*)(Abase + (size_t)(arow0 + lr) * 1536 + k0 + lc);
    const float4 vb = *(const float4*)(Wq + (size_t)(col0 + lr) * 512 + k0 + lc);
    Ast[lc + 0][lr] = va.x; Ast[lc + 1][lr] = va.y;
    Ast[lc + 2][lr] = va.z; Ast[lc + 3][lr] = va.w;
    Bst[lc + 0][lr] = vb.x; Bst[lc + 1][lr] = vb.y;
    Bst[lc + 2][lr] = vb.z; Bst[lc + 3][lr] = vb.w;
    __syncthreads();
#pragma unroll
    for (int k = 0; k < BK; ++k) {
      const float a0 = Ast[k][ty * 2], a1 = Ast[k][ty * 2 + 1];
      const float b0 = Bst[k][tx * 2], b1 = Bst[k][tx * 2 + 1];
      acc[0][0] += a0 * b0; acc[0][1] += a0 * b1;
      acc[1][0] += a1 * b0; acc[1][1] += a1 * b1;
    }
    __syncthreads();
  }
#pragma unroll
  for (int i = 0; i < 2; ++i) {
    float2 o;
    o.x = acc[i][0]; o.y = acc[i][1];
    *(float2*)(M2T + (size_t)(row0 + ty * 2 + i) * 512 + col0 + tx * 2) = o;
  }
}

// ---------------- kernel 2: gemm_v (blocks 0..511) + build_index (512..1023)
// gemm_v R14-exact: 128x64 tile, 8x8 micro, two 128-thread k-teams
// (in-block split-K), merge V = accT0 + accT1 via LDS.
__global__ __launch_bounds__(256) void gemmv_and_index(
    const float* __restrict__ hs, const float* __restrict__ hd,
    const int* __restrict__ cur, const float* __restrict__ Bm,
    float* __restrict__ C,
    const int* __restrict__ neigh, const int* __restrict__ lens,
    int* __restrict__ cnt, int* __restrict__ bucket,
    int* __restrict__ ovf_cnt, int* __restrict__ ovf_list) {
  const int bid = blockIdx.x;
  const int tid = threadIdx.x;
  if (bid >= 512) {
    // ---- build_index part ----
    const int t = (bid - 512) * 256 + tid;   // t in [0, B*M)
    const int b = t >> 5, m = t & 31;
    if (m < lens[b]) {
      const int n = neigh[t];
      const int slot = atomicAdd(&cnt[n], 1);
      if (slot < CAP) bucket[n * CAP + slot] = t;
      else { const int o = atomicAdd(ovf_cnt, 1); ovf_list[o] = t; }
    }
    return;
  }
  // ---- gemm_v part ----
  __shared__ __align__(16) char smem[51200];
  float* As = (float*)smem;              // [2][32][132] = 33792 B
  float* Bs = (float*)(smem + 33792);    // [2][32][68]  = 17408 B
  float* mg = (float*)smem;              // [128][65] merge, aliases As

  const int team = tid >> 7;             // k-half
  const int lt = tid & 127;
  const int swz = (bid & 7) * 64 + (bid >> 3);  // 512 % 8 == 0
  const int row0 = (swz >> 4) * 128;     // 32 row-tiles
  const int col0 = (swz & 15) * 64;      // 16 col-tiles
  const int tx = tid & 7;                // c-block 0..7
  const int ty = (tid >> 3) & 15;        // r-block 0..15
  const int r0 = lt >> 3;                // staging row base 0..15
  const int cq = (lt & 7) * 4;           // staging k-offset 0,4,..,28
  const int kb = team * 256;
  const int aoff = team * 4224;          // 32*132
  const int boff = team * 2176;          // 32*68

  size_t na[8];
#pragma unroll
  for (int p = 0; p < 8; ++p)
    na[p] = (size_t)cur[row0 + r0 + 16 * p] * HDIM + kb + cq;
  const float* bbase = Bm + (size_t)(col0 + r0) * 512 + kb + cq;

  float acc[8][8] = {};
#pragma unroll 1
  for (int t = 0; t < 8; ++t) {
    const int k0 = t * 32;
    float4 va[8], vd[8], vb[4];
#pragma unroll
    for (int p = 0; p < 8; ++p) {
      va[p] = *(const float4*)(hs + na[p] + k0);
      vd[p] = *(const float4*)(hd + na[p] + k0);
    }
#pragma unroll
    for (int p = 0; p < 4; ++p)
      vb[p] = *(const float4*)(bbase + p * (16 * 512) + k0);
    __syncthreads();   // previous tile's compute finished before overwrite
#pragma unroll
    for (int p = 0; p < 8; ++p) {
      const int r = r0 + 16 * p;
      As[aoff + (cq + 0) * 132 + r] = va[p].x + vd[p].x;
      As[aoff + (cq + 1) * 132 + r] = va[p].y + vd[p].y;
      As[aoff + (cq + 2) * 132 + r] = va[p].z + vd[p].z;
      As[aoff + (cq + 3) * 132 + r] = va[p].w + vd[p].w;
    }
#pragma unroll
    for (int p = 0; p < 4; ++p) {
      const int r = r0 + 16 * p;
      Bs[boff + (cq + 0) * 68 + r] = vb[p].x;
      Bs[boff + (cq + 1) * 68 + r] = vb[p].y;
      Bs[boff + (cq + 2) * 68 + r] = vb[p].z;
      Bs[boff + (cq + 3) * 68 + r] = vb[p].w;
    }
    __syncthreads();
#pragma unroll
    for (int k = 0; k < 32; ++k) {
      const float4 a0 = *(const float4*)&As[aoff + k * 132 + ty * 8];
      const float4 a1 = *(const float4*)&As[aoff + k * 132 + ty * 8 + 4];
      const float4 b0 = *(const float4*)&Bs[boff + k * 68 + tx * 8];
      const float4 b1 = *(const float4*)&Bs[boff + k * 68 + tx * 8 + 4];
      const float a[8] = {a0.x, a0.y, a0.z, a0.w, a1.x, a1.y, a1.z, a1.w};
      const float bb[8] = {b0.x, b0.y, b0.z, b0.w, b1.x, b1.y, b1.z, b1.w};
#pragma unroll
      for (int i = 0; i < 8; ++i)
#pragma unroll
        for (int j = 0; j < 8; ++j) acc[i][j] += a[i] * bb[j];
    }
  }
  __syncthreads();   // all compute done; safe to reuse As as merge buffer
  if (team == 1) {
#pragma unroll
    for (int i = 0; i < 8; ++i)
#pragma unroll
      for (int j = 0; j < 8; ++j)
        mg[lt * 65 + i * 8 + j] = acc[i][j];
  }
  __syncthreads();
  if (team == 0) {
#pragma unroll
    for (int i = 0; i < 8; ++i) {
#pragma unroll
      for (int j = 0; j < 8; ++j)
        acc[i][j] = acc[i][j] + mg[lt * 65 + i * 8 + j];  // T0 + T1 order
      float* cp = C + (size_t)(row0 + ty * 8 + i) * 1024 + col0 + tx * 8;
      float4 o0, o1;
      o0.x = acc[i][0]; o0.y = acc[i][1]; o0.z = acc[i][2]; o0.w = acc[i][3];
      o1.x = acc[i][4]; o1.y = acc[i][5]; o1.z = acc[i][6]; o1.w = acc[i][7];
      *(float4*)cp = o0;
      *(float4*)(cp + 4) = o1;
    }
  }
}

// ---------------- streaming compat: one wave per node + ovf drain ----------
// hs/hd loads hoisted unconditionally -> contiguous 256MB sequential stream;
// dot/store guarded by c!=0 -> outputs bit-identical.
__global__ __launch_bounds__(256) void stream_compat(
    const float* __restrict__ hs, const float* __restrict__ hd,
    const float* __restrict__ V, const int* __restrict__ cnt,
    const int* __restrict__ bucket, const int* __restrict__ ovf_cnt,
    const int* __restrict__ ovf_list, const int* __restrict__ neigh,
    float* __restrict__ compat) {
  const int n = blockIdx.x * 4 + (threadIdx.x >> 6);   // node per wave
  const int lane = threadIdx.x & 63;
  const int c = cnt[n];
  const v4f* a4 = (const v4f*)(hs + (size_t)n * HDIM);
  const v4f* c4 = (const v4f*)(hd + (size_t)n * HDIM);
  const v4f a0 = __builtin_nontemporal_load(a4 + lane * 2);
  const v4f a1 = __builtin_nontemporal_load(a4 + lane * 2 + 1);
  const v4f b0 = __builtin_nontemporal_load(c4 + lane * 2);
  const v4f b1 = __builtin_nontemporal_load(c4 + lane * 2 + 1);
  if (c != 0) {
    const int cc = (c < CAP) ? c : CAP;
    for (int e = 0; e < cc; ++e) {
      const int t = bucket[n * CAP + e];
      const int b = t >> 5;
      const float4* vrow = (const float4*)(V + (size_t)b * (2 * HDIM));
      const float4 w0 = vrow[lane * 2], w1 = vrow[lane * 2 + 1];
      const float4 u0 = vrow[128 + lane * 2], u1 = vrow[128 + lane * 2 + 1];
      float acc = a0.x * w0.x + a0.y * w0.y + a0.z * w0.z + a0.w * w0.w
                + a1.x * w1.x + a1.y * w1.y + a1.z * w1.z + a1.w * w1.w
                + b0.x * u0.x + b0.y * u0.y + b0.z * u0.z + b0.w * u0.w
                + b1.x * u1.x + b1.y * u1.y + b1.z * u1.z + b1.w * u1.w;
#pragma unroll
      for (int off = 32; off >= 1; off >>= 1) acc += __shfl_xor(acc, off);
      if (lane == 0) compat[t] = acc;
    }
  }
  // overflow drain (ovf is ~always empty; disjoint t-set -> no race)
  if (blockIdx.x < 32) {
    const int nw = *ovf_cnt;
    for (int e = blockIdx.x * 4 + (threadIdx.x >> 6); e < nw; e += 128) {
      const int t = ovf_list[e];
      const int b = t >> 5;
      const int nn = neigh[t];
      const float4* aa4 = (const float4*)(hs + (size_t)nn * HDIM);
      const float4* cc4 = (const float4*)(hd + (size_t)nn * HDIM);
      const float4 oa0 = aa4[lane * 2], oa1 = aa4[lane * 2 + 1];
      const float4 ob0 = cc4[lane * 2], ob1 = cc4[lane * 2 + 1];
      const float4* vrow = (const float4*)(V + (size_t)b * (2 * HDIM));
      const float4 w0 = vrow[lane * 2], w1 = vrow[lane * 2 + 1];
      const float4 u0 = vrow[128 + lane * 2], u1 = vrow[128 + lane * 2 + 1];
      float acc = oa0.x * w0.x + oa0.y * w0.y + oa0.z * w0.z + oa0.w * w0.w
                + oa1.x * w1.x + oa1.y * w1.y + oa1.z * w1.z + oa1.w * w1.w
                + ob0.x * u0.x + ob0.y * u0.y + ob0.z * u0.z + ob0.w * u0.w
                + ob1.x * u1.x + ob1.y * u1.y + ob1.z * u1.z + ob1.w * u1.w;
#pragma unroll
      for (int off = 32; off >= 1; off >>= 1) acc += __shfl_xor(acc, off);
      if (lane == 0) compat[t] = acc;
    }
  }
}

// ---------------- per-b: Gumbel argmax + log-softmax (one wave per b) ------
__global__ __launch_bounds__(256) void finalize_kernel(
    const float* __restrict__ compat, const int* __restrict__ neigh,
    const int* __restrict__ lengths, const int* __restrict__ cur,
    float* __restrict__ out) {
  const int b = blockIdx.x * 4 + (threadIdx.x >> 6);
  const int tid = threadIdx.x & 63;
  const int len = lengths[b];
  const bool valid = tid < NM;
  const float NEGMAX = -3.402823466e38f;
  float logit = NEGMAX;
  if (valid) {
    const float cm = compat[b * NM + tid] / 22.62741699796952f;  // / sqrt(512)
    logit = (tid < len) ? cm : -1e9f;
  }
  float z = NEGMAX;
  int zi = 1 << 20;
  if (valid) {
    // JAX partitionable threefry: counter = 64-bit flat index,
    // draw = out0 ^ out1 of threefry2x32(key=(0,1), (hi, lo)).
    const unsigned i_lo = (unsigned)b * 32u + (unsigned)tid;
    unsigned x0 = 0u;
    unsigned x1 = i_lo;
    threefry2x32(x0, x1);
    const unsigned bits = x0 ^ x1;
    const float fu = __uint_as_float((bits >> 9) | 0x3f800000u) - 1.0f;
    const float uu = fmaxf(1e-8f, fu + 1e-8f);
    const float g = -logf(-logf(uu));
    z = logit + g;
    zi = tid;
  }
#pragma unroll
  for (int off = 32; off >= 1; off >>= 1) {
    const float oz = __shfl_xor(z, off);
    const int oi = __shfl_xor(zi, off);
    if (oz > z || (oz == z && oi < zi)) { z = oz; zi = oi; }
  }
  float ml = logit;
#pragma unroll
  for (int off = 32; off >= 1; off >>= 1) ml = fmaxf(ml, __shfl_xor(ml, off));
  float ex = valid ? expf(logit - ml) : 0.f;
#pragma unroll
  for (int off = 32; off >= 1; off >>= 1) ex += __shfl_xor(ex, off);
  const float lsel = __shfl(logit, zi);
  if (tid == 0) {
    float lp = lsel - ml - logf(ex);
    int act = neigh[b * NM + zi];
    if (len <= 0) { act = cur[b]; lp = 0.f; }
    out[b] = (float)act;
    out[NBATCH + b] = lp;
  }
}

extern "C" void kernel_launch(void* const* d_in, const int* in_sizes, int n_in,
                              void* d_out, int out_size, void* d_ws, size_t ws_size,
                              hipStream_t stream) {
  const float* hs = (const float*)d_in[0];
  const float* hd = (const float*)d_in[1];
  const float* Ws = (const float*)d_in[2];
  const float* Wd = (const float*)d_in[3];
  const float* Wq = (const float*)d_in[4];
  const int* cur = (const int*)d_in[6];
  const int* neigh = (const int*)d_in[7];
  const int* lens = (const int*)d_in[8];
  float* out = (float*)d_out;

  char* ws = (char*)d_ws;
  size_t off = 0;
  int* cnt = (int*)(ws + off);        off += (size_t)NNODE * 4;        // 256 KB
  int* ovf_cnt = (int*)(ws + off);    off += 256;                      // pad
  int* bucket = (int*)(ws + off);     off += (size_t)NNODE * CAP * 4;  // 4 MB
  int* ovf_list = (int*)(ws + off);   off += (size_t)NBATCH * NM * 4;  // 512 KB
  float* compat = (float*)(ws + off); off += (size_t)NBATCH * NM * 4;  // 512 KB
  float* M2T = (float*)(ws + off);    off += (size_t)1024 * 512 * 4;       // 2 MB
  float* V = (float*)(ws + off);      off += (size_t)NBATCH * 1024 * 4;    // 16 MB

  hipLaunchKernelGGL(zero_and_b1, dim3(64 + 512), dim3(256), 0, stream,
                     Ws, Wd, Wq, M2T, cnt, ovf_cnt);
  hipLaunchKernelGGL(gemmv_and_index, dim3(512 + NBATCH * NM / 256), dim3(256), 0, stream,
                     hs, hd, cur, M2T, V, neigh, lens, cnt, bucket, ovf_cnt, ovf_list);
  hipLaunchKernelGGL(stream_compat, dim3(NNODE / 4), dim3(256), 0, stream,
                     hs, hd, V, cnt, bucket, ovf_cnt, ovf_list, neigh, compat);
  hipLaunchKernelGGL(finalize_kernel, dim3(NBATCH / 4), dim3(256), 0, stream,
                     compat, neigh, lens, cur, out);
}